// Round 10
// baseline (192.397 us; speedup 1.0000x reference)
//
#include <hip/hip_runtime.h>

// MHA: B=2, T=2048, E=1024, H=16, Dh=64. bf16 MFMA pipeline, fp32 I/O.
// R21 == R20 resubmitted (R20 bench died on container acquisition, not the
//      kernel; re-audit: loop terminates, no atomics/barriers in KV loop,
//      VGPR under cap, addressing in-bounds, swizzle bijective).
// R20: k_attn = R19's verified 32x32 swapped-QK^T + in-reg softmax core, but
//      K/V frags loaded straight from global into REGISTER double-buffers
//      (named A/B sets, unroll-2: rule #20), issued one full iteration ahead.
//      ZERO __syncthreads in the KV loop — the 42-49us invariant across R5-R19
//      was the barrier'd LDS stage->vmcnt(0)drain->compute lockstep; registers
//      are wave-private so no cross-wave visibility barrier is needed, and the
//      compiler emits counted vmcnt (T4) automatically for the in-flight set.
//      NOT R13 redux: V prefetched a full iter ahead (R13's was same-iter),
//      32x32 frags are line-exact coalesced (K: 2 full 64B lines/row; V^T:
//      64B-aligned, both ks chunks in one line), and a bijective XCD swizzle
//      co-locates all 16 i-blocks of each (h,bb) on one XCD -> 512KB KV set
//      L2-resident -> ~200cy loads, FETCH ~97->~30MB.
//      Fail criterion (pre-committed): k_attn >= 45us -> floor declared.
//      conv/qkv/oproj unchanged.
#define B_ 2
#define T_ 2048
#define E_ 1024
#define H_ 16
#define DH 64

typedef unsigned short u16;
typedef unsigned int u32;
typedef __bf16 bf16x8 __attribute__((ext_vector_type(8)));
typedef float f32x4 __attribute__((ext_vector_type(4)));
typedef float f32x16 __attribute__((ext_vector_type(16)));

__device__ __forceinline__ u16 f2bf(float f) {
  u32 u = __builtin_bit_cast(u32, f);
  u = u + 0x7FFFu + ((u >> 16) & 1u);
  return (u16)(u >> 16);
}
__device__ __forceinline__ bf16x8 ldfrag(const u16* p) { return *(const bf16x8*)p; }

__device__ __forceinline__ void gload_lds16(const u16* g, u16* l) {
  __builtin_amdgcn_global_load_lds((const __attribute__((address_space(1))) u32*)g,
                                   (__attribute__((address_space(3))) u32*)l, 16, 0, 0);
}

// ---- all input conversions in one kernel ----
__global__ __launch_bounds__(256) void k_conv_all(const float* __restrict__ x,
                                                  const float* __restrict__ Wq,
                                                  const float* __restrict__ Wk,
                                                  const float* __restrict__ Wv,
                                                  const float* __restrict__ wo_w,
                                                  u16* __restrict__ xb, u16* __restrict__ wT,
                                                  u16* __restrict__ woB) {
  __shared__ __align__(16) u16 Ls[64][68];
  const int t = threadIdx.x;
  const int bx = blockIdx.x;
  if (bx < 2048 || bx >= 2816) {  // plain cast, 8 elems/thread
    const float* src = (bx < 2048) ? x : wo_w;
    u16* dst = (bx < 2048) ? xb : woB;
    u32 i = (((bx < 2048) ? bx : (bx - 2816)) * 256u + t) * 8u;
    float4 a = *(const float4*)(src + i);
    float4 b = *(const float4*)(src + i + 4);
    uint4 v;
    v.x = (u32)f2bf(a.x) | ((u32)f2bf(a.y) << 16);
    v.y = (u32)f2bf(a.z) | ((u32)f2bf(a.w) << 16);
    v.z = (u32)f2bf(b.x) | ((u32)f2bf(b.y) << 16);
    v.w = (u32)f2bf(b.z) | ((u32)f2bf(b.w) << 16);
    *(uint4*)(dst + i) = v;
    return;
  }
  // Wq/Wk/Wv [H,E,Dh] fp32 -> [3][H,Dh,E] bf16 via LDS tile; Wq gets 0.125*log2e.
  const int idx = bx - 2048;
  const int e0 = (idx & 15) * 64;
  const int h = (idx >> 4) & 15;
  const int which = idx >> 8;
  const float* src = (which == 0) ? Wq : ((which == 1) ? Wk : Wv);
  const float scale = (which == 0) ? 0.18033688011112042f : 1.0f;
#pragma unroll
  for (int p = 0; p < 4; p++) {
    int id2 = p * 256 + t;
    int row = id2 >> 4, ch = id2 & 15;
    float4 v = *(const float4*)(src + ((size_t)h * E_ + e0 + row) * DH + ch * 4);
    uint2 pk;
    pk.x = (u32)f2bf(v.x * scale) | ((u32)f2bf(v.y * scale) << 16);
    pk.y = (u32)f2bf(v.z * scale) | ((u32)f2bf(v.w * scale) << 16);
    *(uint2*)(&Ls[row][ch * 4]) = pk;
  }
  __syncthreads();
  u16* dst = wT + ((size_t)which * H_ + h) * (DH * E_);
#pragma unroll
  for (int p = 0; p < 4; p++) {
    int id2 = p * 256 + t;
    int d = id2 >> 4, ec = id2 & 15;
    uint2 pk;
    pk.x = (u32)Ls[ec * 4 + 0][d] | ((u32)Ls[ec * 4 + 1][d] << 16);
    pk.y = (u32)Ls[ec * 4 + 2][d] | ((u32)Ls[ec * 4 + 3][d] << 16);
    *(uint2*)(dst + (size_t)d * E_ + e0 + ec * 4) = pk;
  }
}

// ---- fused QKV GEMM: C[4096,3072] = X[4096,1024] * W^T (W as [3072][1024] bf16) ----
__global__ __launch_bounds__(256, 3) void k_qkv(const u16* __restrict__ xb, const u16* __restrict__ wT,
                                                u16* __restrict__ Qb, u16* __restrict__ Kb,
                                                u16* __restrict__ VbT) {
  __shared__ __align__(16) u16 As[128 * 64];
  __shared__ __align__(16) u16 Bs[128 * 64];
  const int tid = threadIdx.x;
  const int w = tid >> 6, lane = tid & 63, quad = lane >> 4, lr = lane & 15;
  const int wr = w >> 1, wc = w & 1;
  const int bid = blockIdx.x;
  const int xcd = bid & 7, bidx = bid >> 3;   // bidx in [0,96)
  const int t0 = (xcd * 4 + bidx / 24) * 128; // row-tile in [0,32)
  const int n0 = (bidx % 24) * 128;           // col-tile in [0,24)
  const int sr = lane >> 3, sc = lane & 7;

  f32x4 acc[4][4];
  const f32x4 z4 = {0.f, 0.f, 0.f, 0.f};
#pragma unroll
  for (int i = 0; i < 4; i++)
#pragma unroll
    for (int j = 0; j < 4; j++) acc[i][j] = z4;

  for (int k0 = 0; k0 < E_; k0 += 64) {
    __syncthreads();
#pragma unroll
    for (int ii = 0; ii < 4; ii++) {
      int ra = w * 32 + ii * 8 + sr;
      gload_lds16(xb + (size_t)(t0 + ra) * E_ + k0 + ((sc ^ (ra & 7)) << 3),
                  As + (w * 32 + ii * 8) * 64);
      gload_lds16(wT + (size_t)(n0 + ra) * E_ + k0 + ((sc ^ (ra & 7)) << 3),
                  Bs + (w * 32 + ii * 8) * 64);
    }
    __syncthreads();
#pragma unroll
    for (int kk = 0; kk < 2; kk++) {
      bf16x8 af[4], bfv[4];
#pragma unroll
      for (int rt = 0; rt < 4; rt++) {
        int row = wr * 64 + rt * 16 + lr;
        af[rt] = ldfrag(As + row * 64 + (((kk * 4 + quad) ^ (row & 7)) << 3));
      }
#pragma unroll
      for (int ct = 0; ct < 4; ct++) {
        int row = wc * 64 + ct * 16 + lr;
        bfv[ct] = ldfrag(Bs + row * 64 + (((kk * 4 + quad) ^ (row & 7)) << 3));
      }
#pragma unroll
      for (int rt = 0; rt < 4; rt++)
#pragma unroll
        for (int ct = 0; ct < 4; ct++)
          acc[rt][ct] = __builtin_amdgcn_mfma_f32_16x16x32_bf16(af[rt], bfv[ct], acc[rt][ct], 0, 0, 0);
    }
  }

  const int qkv = n0 >> 10;
  if (qkv < 2) {
    u16* outp = (qkv == 0) ? Qb : Kb;
#pragma unroll
    for (int rt = 0; rt < 4; rt++)
#pragma unroll
      for (int ct = 0; ct < 4; ct++) {
        int n = n0 + wc * 64 + ct * 16 + lr;
        int h = (n >> 6) & 15, d = n & 63;
#pragma unroll
        for (int r = 0; r < 4; r++) {
          int t = t0 + wr * 64 + rt * 16 + quad * 4 + r;
          int bb = t >> 11, tt = t & 2047;
          outp[(((size_t)bb * H_ + h) * T_ + tt) * DH + d] = f2bf(acc[rt][ct][r]);
        }
      }
  } else {
#pragma unroll
    for (int rt = 0; rt < 4; rt++)
#pragma unroll
      for (int ct = 0; ct < 4; ct++) {
        int n = n0 + wc * 64 + ct * 16 + lr;
        int h = (n >> 6) & 15, d = n & 63;
        int t = t0 + wr * 64 + rt * 16 + quad * 4;
        int bb = t >> 11, tt = t & 2047;
        uint2 pk;
        pk.x = (u32)f2bf(acc[rt][ct][0]) | ((u32)f2bf(acc[rt][ct][1]) << 16);
        pk.y = (u32)f2bf(acc[rt][ct][2]) | ((u32)f2bf(acc[rt][ct][3]) << 16);
        *(uint2*)(VbT + (((size_t)bb * H_ + h) * DH + d) * T_ + tt) = pk;
      }
  }
}

// ---- flash attention: 32x32 swapped-QK^T, in-reg softmax, register-prefetched
//      K/V (no LDS staging, no barriers in KV loop) ----
// 1-D grid 512, XCD swizzle: xcd=bid&7 hosts hb = xcd*4+(k>>4) (4 per XCD),
// i-pair = k&15 -> all 16 i-blocks of one (h,bb) share one XCD's L2 (512KB WS).
// Waves = (qhalf, shalf). Fixed-max p=exp2(s-20): s-half partials ADD; combined
// per q-tile via LDS (outside loop). Layouts verified in R19.
__global__ __launch_bounds__(256, 2) void k_attn(const u16* __restrict__ Qb, const u16* __restrict__ Kb,
                                                 const u16* __restrict__ VbT, u16* __restrict__ AO) {
  __shared__ __align__(16) float Lo[4096];  // 16 KB combine buffer
  __shared__ float Ll[128];

  const int tid = threadIdx.x;
  const int w = tid >> 6, lane = tid & 63;
  const int l31 = lane & 31, hi = lane >> 5;
  const int qhalf = w & 1, shalf = w >> 1;
  const int bid = blockIdx.x;
  const int xcd = bid & 7, kdec = bid >> 3;   // kdec in [0,64)
  const int hb = xcd * 4 + (kdec >> 4);       // [0,32)
  const int i = kdec & 15;                    // pair (31-i, i)
  const int h = hb & 15, bb = hb >> 4;
  const u16* qb = Qb + ((size_t)bb * H_ + h) * (size_t)(T_ * DH);
  const u16* kbp = Kb + ((size_t)bb * H_ + h) * (size_t)(T_ * DH);
  const u16* vbT = VbT + ((size_t)bb * H_ + h) * (size_t)(T_ * DH);  // [DH][T]
  const float MFIX = 20.0f;

  // per-lane frag bases (verified R19 mapping, de-swizzled to global):
  // K A-frag ki: kfrag + j0*64 + ki*16  (row shalf*32+l31, k = ki*16+hi*8+j)
  const u16* kfrag = kbp + (size_t)(shalf * 32 + l31) * DH + hi * 8;
  // V A-frag (ks, dhalf): vfrag{0,1} + j0 + ks*16  (col s = j0+shalf*32+ks*16+hi*8+j)
  const u16* vfrag0 = vbT + (size_t)l31 * T_ + shalf * 32 + hi * 8;
  const u16* vfrag1 = vbT + (size_t)(32 + l31) * T_ + shalf * 32 + hi * 8;

#define LOADT(K0, K1, K2, K3, V0, V1, V2, V3, J0)                        \
  do {                                                                   \
    const u16* kp_ = kfrag + (size_t)(J0) * DH;                          \
    K0 = ldfrag(kp_); K1 = ldfrag(kp_ + 16);                             \
    K2 = ldfrag(kp_ + 32); K3 = ldfrag(kp_ + 48);                        \
    V0 = ldfrag(vfrag0 + (J0)); V1 = ldfrag(vfrag0 + (J0) + 16);         \
    V2 = ldfrag(vfrag1 + (J0)); V3 = ldfrag(vfrag1 + (J0) + 16);         \
  } while (0)

#define COMPT(K0, K1, K2, K3, V0, V1, V2, V3, JT)                            \
  do {                                                                       \
    f32x16 s_acc = {};                                                       \
    __builtin_amdgcn_s_setprio(1);                                           \
    s_acc = __builtin_amdgcn_mfma_f32_32x32x16_bf16(K0, bq[0], s_acc, 0, 0, 0); \
    s_acc = __builtin_amdgcn_mfma_f32_32x32x16_bf16(K1, bq[1], s_acc, 0, 0, 0); \
    s_acc = __builtin_amdgcn_mfma_f32_32x32x16_bf16(K2, bq[2], s_acc, 0, 0, 0); \
    s_acc = __builtin_amdgcn_mfma_f32_32x32x16_bf16(K3, bq[3], s_acc, 0, 0, 0); \
    __builtin_amdgcn_s_setprio(0);                                           \
    if ((JT) == qt) { /* diagonal mask: s_abs > q_abs */                     \
      _Pragma("unroll") for (int r16 = 0; r16 < 16; r16++) {                 \
        int s_abs = (JT) * 64 + shalf * 32 + (r16 & 3) + 8 * (r16 >> 2) + 4 * hi; \
        if (s_abs > q_abs) s_acc[r16] = -__builtin_inff();                   \
      }                                                                      \
    }                                                                        \
    float p_[16]; float rsum_ = 0.f;                                         \
    _Pragma("unroll") for (int r16 = 0; r16 < 16; r16++) {                   \
      p_[r16] = __builtin_amdgcn_exp2f(s_acc[r16] - MFIX);                   \
      rsum_ += p_[r16];                                                      \
    }                                                                        \
    l_i += rsum_;                                                            \
    u32 a_[8], xch_[8];                                                      \
    _Pragma("unroll") for (int g = 0; g < 8; g++)                            \
      a_[g] = (__builtin_bit_cast(u32, p_[2 * g]) >> 16) |                   \
              (__builtin_bit_cast(u32, p_[2 * g + 1]) & 0xffff0000u);        \
    _Pragma("unroll") for (int g = 0; g < 8; g++) xch_[g] = __shfl_xor(a_[g], 32); \
    __builtin_amdgcn_s_setprio(1);                                           \
    {                                                                        \
      uint4 fu;                                                              \
      fu.x = hi ? xch_[2] : a_[0]; fu.y = hi ? xch_[3] : a_[1];              \
      fu.z = hi ? a_[2] : xch_[0]; fu.w = hi ? a_[3] : xch_[1];              \
      bf16x8 bp = __builtin_bit_cast(bf16x8, fu);                            \
      o0 = __builtin_amdgcn_mfma_f32_32x32x16_bf16(V0, bp, o0, 0, 0, 0);     \
      o1 = __builtin_amdgcn_mfma_f32_32x32x16_bf16(V2, bp, o1, 0, 0, 0);     \
    }                                                                        \
    {                                                                        \
      uint4 fu;                                                              \
      fu.x = hi ? xch_[6] : a_[4]; fu.y = hi ? xch_[7] : a_[5];              \
      fu.z = hi ? a_[6] : xch_[4]; fu.w = hi ? a_[7] : xch_[5];              \
      bf16x8 bp = __builtin_bit_cast(bf16x8, fu);                            \
      o0 = __builtin_amdgcn_mfma_f32_32x32x16_bf16(V1, bp, o0, 0, 0, 0);     \
      o1 = __builtin_amdgcn_mfma_f32_32x32x16_bf16(V3, bp, o1, 0, 0, 0);     \
    }                                                                        \
    __builtin_amdgcn_s_setprio(0);                                           \
  } while (0)

  for (int jb = 0; jb < 2; jb++) {
    const int qt = jb ? i : (31 - i);
    const int t0 = qt * 64;
    const int q_abs = t0 + qhalf * 32 + l31;

    // Q B-frags (pre-scaled 0.125*log2e): B[k=ki*16+hi*8+j][n=q=l31]
    const u16* qrow = qb + (size_t)q_abs * DH;
    bf16x8 bq[4];
#pragma unroll
    for (int ki = 0; ki < 4; ki++) bq[ki] = ldfrag(qrow + ki * 16 + hi * 8);

    f32x16 o0 = {}, o1 = {};
    float l_i = 0.f;

    bf16x8 A0, A1, A2, A3, AV0, AV1, AV2, AV3;
    bf16x8 B0, B1, B2, B3, BV0, BV1, BV2, BV3;

    LOADT(A0, A1, A2, A3, AV0, AV1, AV2, AV3, 0);
    int jt = 0;
    while (true) {
      if (jt + 1 <= qt) LOADT(B0, B1, B2, B3, BV0, BV1, BV2, BV3, (jt + 1) * 64);
      COMPT(A0, A1, A2, A3, AV0, AV1, AV2, AV3, jt);
      jt++;
      if (jt > qt) break;
      if (jt + 1 <= qt) LOADT(A0, A1, A2, A3, AV0, AV1, AV2, AV3, (jt + 1) * 64);
      COMPT(B0, B1, B2, B3, BV0, BV1, BV2, BV3, jt);
      jt++;
      if (jt > qt) break;
    }

    // combine s-half partials: wave pairs (0,2),(1,3) share q; fixed-max => ADD
    __syncthreads();  // previous q-tile's combine reads done
    if (shalf) {
      float* base = Lo + qhalf * 2048 + lane * 32;
#pragma unroll
      for (int g = 0; g < 4; g++) {
        float4 v = {o0[4 * g + 0], o0[4 * g + 1], o0[4 * g + 2], o0[4 * g + 3]};
        *(float4*)(base + ((g ^ (lane & 7)) << 2)) = v;
      }
#pragma unroll
      for (int g = 4; g < 8; g++) {
        float4 v = {o1[4 * g - 16], o1[4 * g - 15], o1[4 * g - 14], o1[4 * g - 13]};
        *(float4*)(base + ((g ^ (lane & 7)) << 2)) = v;
      }
      Ll[qhalf * 64 + lane] = l_i;
    }
    __syncthreads();
    if (!shalf) {
      float* base = Lo + qhalf * 2048 + lane * 32;
#pragma unroll
      for (int g = 0; g < 4; g++) {
        float4 v = *(float4*)(base + ((g ^ (lane & 7)) << 2));
        o0[4 * g + 0] += v.x; o0[4 * g + 1] += v.y;
        o0[4 * g + 2] += v.z; o0[4 * g + 3] += v.w;
      }
#pragma unroll
      for (int g = 4; g < 8; g++) {
        float4 v = *(float4*)(base + ((g ^ (lane & 7)) << 2));
        o1[4 * g - 16] += v.x; o1[4 * g - 15] += v.y;
        o1[4 * g - 14] += v.z; o1[4 * g - 13] += v.w;
      }
      l_i += Ll[qhalf * 64 + lane];
      l_i += __shfl_xor(l_i, 32);  // combine hi halves (same q)
      float inv = 1.0f / l_i;
      u16* orow = AO + ((size_t)bb * T_ + q_abs) * E_ + h * DH;
#pragma unroll
      for (int g = 0; g < 4; g++) {
        uint2 pk;
        pk.x = (u32)f2bf(o0[4 * g + 0] * inv) | ((u32)f2bf(o0[4 * g + 1] * inv) << 16);
        pk.y = (u32)f2bf(o0[4 * g + 2] * inv) | ((u32)f2bf(o0[4 * g + 3] * inv) << 16);
        *(uint2*)(orow + 8 * g + 4 * hi) = pk;
        pk.x = (u32)f2bf(o1[4 * g + 0] * inv) | ((u32)f2bf(o1[4 * g + 1] * inv) << 16);
        pk.y = (u32)f2bf(o1[4 * g + 2] * inv) | ((u32)f2bf(o1[4 * g + 3] * inv) << 16);
        *(uint2*)(orow + 32 + 8 * g + 4 * hi) = pk;
      }
    }
  }
#undef LOADT
#undef COMPT
}

// ---- output projection, 128x64 tiles, XCD-banded: out = AO @ wo^T + b ----
__global__ __launch_bounds__(256, 3) void k_oproj(const u16* __restrict__ AO, const u16* __restrict__ woB,
                                                  const float* __restrict__ bias, float* __restrict__ out) {
  __shared__ __align__(16) u16 As[128 * 64];  // 16 KB
  __shared__ __align__(16) u16 Bs[64 * 64];   //  8 KB
  const int tid = threadIdx.x;
  const int w = tid >> 6, lane = tid & 63, quad = lane >> 4, lr = lane & 15;
  const int wr = w >> 1, wc = w & 1;
  const int bid = blockIdx.x;
  const int xcd = bid & 7, bidx = bid >> 3;      // bidx in [0,64)
  const int r0 = (xcd * 4 + (bidx >> 4)) * 128;  // row-tile in [0,32)
  const int n0 = (bidx & 15) * 64;               // col-tile in [0,16)
  const int sr = lane >> 3, sc = lane & 7;

  f32x4 acc[4][2];
  const f32x4 z4 = {0.f, 0.f, 0.f, 0.f};
#pragma unroll
  for (int i = 0; i < 4; i++) {
    acc[i][0] = z4;
    acc[i][1] = z4;
  }

  for (int k0 = 0; k0 < E_; k0 += 64) {
    __syncthreads();
#pragma unroll
    for (int ii = 0; ii < 4; ii++) {  // A: 128 rows, wave stages 32
      int ra = w * 32 + ii * 8 + sr;
      gload_lds16(AO + (size_t)(r0 + ra) * E_ + k0 + ((sc ^ (ra & 7)) << 3),
                  As + (w * 32 + ii * 8) * 64);
    }
#pragma unroll
    for (int ii = 0; ii < 2; ii++) {  // B: 64 rows, wave stages 16
      int rb = w * 16 + ii * 8 + sr;
      gload_lds16(woB + (size_t)(n0 + rb) * E_ + k0 + ((sc ^ (rb & 7)) << 3),
                  Bs + (w * 16 + ii * 8) * 64);
    }
    __syncthreads();
#pragma unroll
    for (int kk = 0; kk < 2; kk++) {
      bf16x8 af[4], bfv[2];
#pragma unroll
      for (int rt = 0; rt < 4; rt++) {
        int row = wr * 64 + rt * 16 + lr;
        af[rt] = ldfrag(As + row * 64 + (((kk * 4 + quad) ^ (row & 7)) << 3));
      }
#pragma unroll
      for (int ct = 0; ct < 2; ct++) {
        int row = wc * 32 + ct * 16 + lr;
        bfv[ct] = ldfrag(Bs + row * 64 + (((kk * 4 + quad) ^ (row & 7)) << 3));
      }
#pragma unroll
      for (int rt = 0; rt < 4; rt++)
#pragma unroll
        for (int ct = 0; ct < 2; ct++)
          acc[rt][ct] = __builtin_amdgcn_mfma_f32_16x16x32_bf16(af[rt], bfv[ct], acc[rt][ct], 0, 0, 0);
    }
  }

#pragma unroll
  for (int ct = 0; ct < 2; ct++) {
    int col = n0 + wc * 32 + ct * 16 + lr;
    float bv = bias[col];
#pragma unroll
    for (int rt = 0; rt < 4; rt++)
#pragma unroll
      for (int r = 0; r < 4; r++) {
        int row = r0 + wr * 64 + rt * 16 + quad * 4 + r;
        out[(size_t)row * E_ + col] = acc[rt][ct][r] + bv;
      }
  }
}

extern "C" void kernel_launch(void* const* d_in, const int* in_sizes, int n_in,
                              void* d_out, int out_size, void* d_ws, size_t ws_size,
                              hipStream_t stream) {
  const float* x = (const float*)d_in[0];
  const float* Wq = (const float*)d_in[1];
  const float* Wk = (const float*)d_in[2];
  const float* Wv = (const float*)d_in[3];
  const float* wo_w = (const float*)d_in[4];
  const float* wo_b = (const float*)d_in[5];
  float* out = (float*)d_out;
  char* ws = (char*)d_ws;

  u16* xb  = (u16*)(ws + 0);          //  8 MiB: x bf16 [B,T,E]
  u16* wT  = (u16*)(ws + 8388608);    //  6 MiB: [3][H,Dh,E] bf16
  u16* woB = (u16*)(ws + 14680064);   //  2 MiB: wo bf16 [E,E]
  u16* Qb  = (u16*)(ws + 16777216);   //  8 MiB: Q [B,H,T,Dh] (pre-scaled 0.125*log2e)
  u16* Kb  = (u16*)(ws + 25165824);   //  8 MiB: K [B,H,T,Dh]
  u16* VbT = (u16*)(ws + 33554432);   //  8 MiB: V^T [B,H,Dh,T]
  u16* AO  = (u16*)(ws + 41943040);   //  8 MiB: attn out bf16 [B,T,E]

  k_conv_all<<<3328, 256, 0, stream>>>(x, Wq, Wk, Wv, wo_w, xb, wT, woB);
  k_qkv<<<768, 256, 0, stream>>>(xb, wT, Qb, Kb, VbT);
  k_attn<<<512, 256, 0, stream>>>(Qb, Kb, VbT, AO);
  k_oproj<<<512, 256, 0, stream>>>(AO, woB, wo_b, out);
}

// Round 11
// 164.710 us; speedup vs baseline: 1.1681x; 1.1681x over previous
//
#include <hip/hip_runtime.h>

// MHA: B=2, T=2048, E=1024, H=16, Dh=64. bf16 MFMA pipeline, fp32 I/O.
// R22: single-variable A/B — R19's k_attn body VERBATIM (best-measured attn,
//      45.1us: LDS-staged K/V + 32x32 swapped-QK^T + in-reg softmax) with
//      R21's XCD-banded grid decode (PROVEN: FETCH 97.3->12.3MB, K/V
//      L2-resident). Theory: R19's per-iter barrier drained HBM-miss staging
//      loads (~900cy); L2-resident staging (~200cy) cuts the drain ~700cy x
//      33 iters ~ 10us/pass. R21 post-mortem: reg-prefetch was silently
//      deleted by the compiler (VGPR=108 < 128-needed for two frag sets under
//      launch_bounds(256,2) cap) -> exposed latency, 71us; that structure is
//      abandoned per pre-commit.
//      Fail criterion (pre-committed): k_attn >= 44us -> attn floor ~45
//      confirmed, config ships as final. conv/qkv/oproj unchanged (R15).
#define B_ 2
#define T_ 2048
#define E_ 1024
#define H_ 16
#define DH 64

typedef unsigned short u16;
typedef unsigned int u32;
typedef __bf16 bf16x8 __attribute__((ext_vector_type(8)));
typedef float f32x4 __attribute__((ext_vector_type(4)));
typedef float f32x16 __attribute__((ext_vector_type(16)));

__device__ __forceinline__ u16 f2bf(float f) {
  u32 u = __builtin_bit_cast(u32, f);
  u = u + 0x7FFFu + ((u >> 16) & 1u);
  return (u16)(u >> 16);
}
__device__ __forceinline__ bf16x8 ldfrag(const u16* p) { return *(const bf16x8*)p; }

__device__ __forceinline__ void gload_lds16(const u16* g, u16* l) {
  __builtin_amdgcn_global_load_lds((const __attribute__((address_space(1))) u32*)g,
                                   (__attribute__((address_space(3))) u32*)l, 16, 0, 0);
}

// ---- all input conversions in one kernel ----
__global__ __launch_bounds__(256) void k_conv_all(const float* __restrict__ x,
                                                  const float* __restrict__ Wq,
                                                  const float* __restrict__ Wk,
                                                  const float* __restrict__ Wv,
                                                  const float* __restrict__ wo_w,
                                                  u16* __restrict__ xb, u16* __restrict__ wT,
                                                  u16* __restrict__ woB) {
  __shared__ __align__(16) u16 Ls[64][68];
  const int t = threadIdx.x;
  const int bx = blockIdx.x;
  if (bx < 2048 || bx >= 2816) {  // plain cast, 8 elems/thread
    const float* src = (bx < 2048) ? x : wo_w;
    u16* dst = (bx < 2048) ? xb : woB;
    u32 i = (((bx < 2048) ? bx : (bx - 2816)) * 256u + t) * 8u;
    float4 a = *(const float4*)(src + i);
    float4 b = *(const float4*)(src + i + 4);
    uint4 v;
    v.x = (u32)f2bf(a.x) | ((u32)f2bf(a.y) << 16);
    v.y = (u32)f2bf(a.z) | ((u32)f2bf(a.w) << 16);
    v.z = (u32)f2bf(b.x) | ((u32)f2bf(b.y) << 16);
    v.w = (u32)f2bf(b.z) | ((u32)f2bf(b.w) << 16);
    *(uint4*)(dst + i) = v;
    return;
  }
  // Wq/Wk/Wv [H,E,Dh] fp32 -> [3][H,Dh,E] bf16 via LDS tile; Wq gets 0.125*log2e.
  const int idx = bx - 2048;
  const int e0 = (idx & 15) * 64;
  const int h = (idx >> 4) & 15;
  const int which = idx >> 8;
  const float* src = (which == 0) ? Wq : ((which == 1) ? Wk : Wv);
  const float scale = (which == 0) ? 0.18033688011112042f : 1.0f;
#pragma unroll
  for (int p = 0; p < 4; p++) {
    int id2 = p * 256 + t;
    int row = id2 >> 4, ch = id2 & 15;
    float4 v = *(const float4*)(src + ((size_t)h * E_ + e0 + row) * DH + ch * 4);
    uint2 pk;
    pk.x = (u32)f2bf(v.x * scale) | ((u32)f2bf(v.y * scale) << 16);
    pk.y = (u32)f2bf(v.z * scale) | ((u32)f2bf(v.w * scale) << 16);
    *(uint2*)(&Ls[row][ch * 4]) = pk;
  }
  __syncthreads();
  u16* dst = wT + ((size_t)which * H_ + h) * (DH * E_);
#pragma unroll
  for (int p = 0; p < 4; p++) {
    int id2 = p * 256 + t;
    int d = id2 >> 4, ec = id2 & 15;
    uint2 pk;
    pk.x = (u32)Ls[ec * 4 + 0][d] | ((u32)Ls[ec * 4 + 1][d] << 16);
    pk.y = (u32)Ls[ec * 4 + 2][d] | ((u32)Ls[ec * 4 + 3][d] << 16);
    *(uint2*)(dst + (size_t)d * E_ + e0 + ec * 4) = pk;
  }
}

// ---- fused QKV GEMM: C[4096,3072] = X[4096,1024] * W^T (W as [3072][1024] bf16) ----
__global__ __launch_bounds__(256, 3) void k_qkv(const u16* __restrict__ xb, const u16* __restrict__ wT,
                                                u16* __restrict__ Qb, u16* __restrict__ Kb,
                                                u16* __restrict__ VbT) {
  __shared__ __align__(16) u16 As[128 * 64];
  __shared__ __align__(16) u16 Bs[128 * 64];
  const int tid = threadIdx.x;
  const int w = tid >> 6, lane = tid & 63, quad = lane >> 4, lr = lane & 15;
  const int wr = w >> 1, wc = w & 1;
  const int bid = blockIdx.x;
  const int xcd = bid & 7, bidx = bid >> 3;   // bidx in [0,96)
  const int t0 = (xcd * 4 + bidx / 24) * 128; // row-tile in [0,32)
  const int n0 = (bidx % 24) * 128;           // col-tile in [0,24)
  const int sr = lane >> 3, sc = lane & 7;

  f32x4 acc[4][4];
  const f32x4 z4 = {0.f, 0.f, 0.f, 0.f};
#pragma unroll
  for (int i = 0; i < 4; i++)
#pragma unroll
    for (int j = 0; j < 4; j++) acc[i][j] = z4;

  for (int k0 = 0; k0 < E_; k0 += 64) {
    __syncthreads();
#pragma unroll
    for (int ii = 0; ii < 4; ii++) {
      int ra = w * 32 + ii * 8 + sr;
      gload_lds16(xb + (size_t)(t0 + ra) * E_ + k0 + ((sc ^ (ra & 7)) << 3),
                  As + (w * 32 + ii * 8) * 64);
      gload_lds16(wT + (size_t)(n0 + ra) * E_ + k0 + ((sc ^ (ra & 7)) << 3),
                  Bs + (w * 32 + ii * 8) * 64);
    }
    __syncthreads();
#pragma unroll
    for (int kk = 0; kk < 2; kk++) {
      bf16x8 af[4], bfv[4];
#pragma unroll
      for (int rt = 0; rt < 4; rt++) {
        int row = wr * 64 + rt * 16 + lr;
        af[rt] = ldfrag(As + row * 64 + (((kk * 4 + quad) ^ (row & 7)) << 3));
      }
#pragma unroll
      for (int ct = 0; ct < 4; ct++) {
        int row = wc * 64 + ct * 16 + lr;
        bfv[ct] = ldfrag(Bs + row * 64 + (((kk * 4 + quad) ^ (row & 7)) << 3));
      }
#pragma unroll
      for (int rt = 0; rt < 4; rt++)
#pragma unroll
        for (int ct = 0; ct < 4; ct++)
          acc[rt][ct] = __builtin_amdgcn_mfma_f32_16x16x32_bf16(af[rt], bfv[ct], acc[rt][ct], 0, 0, 0);
    }
  }

  const int qkv = n0 >> 10;
  if (qkv < 2) {
    u16* outp = (qkv == 0) ? Qb : Kb;
#pragma unroll
    for (int rt = 0; rt < 4; rt++)
#pragma unroll
      for (int ct = 0; ct < 4; ct++) {
        int n = n0 + wc * 64 + ct * 16 + lr;
        int h = (n >> 6) & 15, d = n & 63;
#pragma unroll
        for (int r = 0; r < 4; r++) {
          int t = t0 + wr * 64 + rt * 16 + quad * 4 + r;
          int bb = t >> 11, tt = t & 2047;
          outp[(((size_t)bb * H_ + h) * T_ + tt) * DH + d] = f2bf(acc[rt][ct][r]);
        }
      }
  } else {
#pragma unroll
    for (int rt = 0; rt < 4; rt++)
#pragma unroll
      for (int ct = 0; ct < 4; ct++) {
        int n = n0 + wc * 64 + ct * 16 + lr;
        int h = (n >> 6) & 15, d = n & 63;
        int t = t0 + wr * 64 + rt * 16 + quad * 4;
        int bb = t >> 11, tt = t & 2047;
        uint2 pk;
        pk.x = (u32)f2bf(acc[rt][ct][0]) | ((u32)f2bf(acc[rt][ct][1]) << 16);
        pk.y = (u32)f2bf(acc[rt][ct][2]) | ((u32)f2bf(acc[rt][ct][3]) << 16);
        *(uint2*)(VbT + (((size_t)bb * H_ + h) * DH + d) * T_ + tt) = pk;
      }
  }
}

// ---- flash attention: R19 body (LDS-staged K/V, 32x32 swapped-QK^T, in-reg
//      softmax) + R21 XCD-banded grid decode (K/V L2-resident) ----
// 1-D grid 512: xcd=bid&7 hosts hb=xcd*4+(kdec>>4) (4 (h,bb) per XCD), i-pair
// = kdec&15 -> all 16 i-blocks of one (h,bb) share one XCD's L2 (512KB WS).
__global__ __launch_bounds__(256, 2) void k_attn(const u16* __restrict__ Qb, const u16* __restrict__ Kb,
                                                 const u16* __restrict__ VbT, u16* __restrict__ AO) {
  __shared__ __align__(16) u16 smem[8192];  // Ks[4096] | Vts[4096]; reused as Lo f32[4096]
  __shared__ float Ll[128];
  u16* Ks = smem;
  u16* Vts = smem + 4096;
  float* Lo = (float*)smem;

  const int tid = threadIdx.x;
  const int w = tid >> 6, lane = tid & 63;
  const int l31 = lane & 31, hi = lane >> 5;
  const int qhalf = w & 1, shalf = w >> 1;
  const int srow = lane >> 3, schunk = lane & 7;
  const int bid = blockIdx.x;
  const int xcd = bid & 7, kdec = bid >> 3;   // kdec in [0,64)
  const int hb = xcd * 4 + (kdec >> 4);       // [0,32)
  const int i = kdec & 15;                    // pair (31-i, i)
  const int h = hb & 15, bb = hb >> 4;
  const u16* qb = Qb + ((size_t)bb * H_ + h) * (size_t)(T_ * DH);
  const u16* kb = Kb + ((size_t)bb * H_ + h) * (size_t)(T_ * DH);
  const u16* vbT = VbT + ((size_t)bb * H_ + h) * (size_t)(T_ * DH);  // [DH][T]
  const float MFIX = 20.0f;

  for (int jb = 0; jb < 2; jb++) {
    const int qt = jb ? i : (31 - i);
    const int t0 = qt * 64;
    const int q_abs = t0 + qhalf * 32 + l31;

    // Q B-frags (pre-scaled 0.125*log2e): B[k=ki*16+8*hi+j][n=q=l31]
    const u16* qrow = qb + (size_t)q_abs * DH;
    bf16x8 bq[4];
#pragma unroll
    for (int ki = 0; ki < 4; ki++) bq[ki] = ldfrag(qrow + ki * 16 + hi * 8);

    f32x16 o0 = {}, o1 = {};  // O^T[d=dt*32+...][q], dt=0,1
    float l_i = 0.f;

    for (int jt = 0; jt <= qt; jt++) {
      const int j0 = jt * 64;
      __syncthreads();  // all waves done reading previous K/V (or Lo)
#pragma unroll
      for (int ii = 0; ii < 2; ii++) {  // stage K rows + V^T rows (swizzled)
        int r = w * 16 + ii * 8 + srow;
        gload_lds16(kb + (size_t)(j0 + r) * DH + ((schunk ^ (r & 7)) << 3),
                    Ks + (w * 16 + ii * 8) * 64);
        gload_lds16(vbT + (size_t)r * T_ + j0 + ((schunk ^ (r & 7)) << 3),
                    Vts + (w * 16 + ii * 8) * 64);
      }
      __syncthreads();  // K/V visible

      // St = K·Q^T (32x32): D[m=s_local][n=q]
      f32x16 s_acc = {};
      const int krow = shalf * 32 + l31;
      __builtin_amdgcn_s_setprio(1);
#pragma unroll
      for (int ki = 0; ki < 4; ki++) {
        bf16x8 ak = ldfrag(Ks + krow * 64 + (((2 * ki + hi) ^ (krow & 7)) << 3));
        s_acc = __builtin_amdgcn_mfma_f32_32x32x16_bf16(ak, bq[ki], s_acc, 0, 0, 0);
      }
      __builtin_amdgcn_s_setprio(0);

      if (jt == qt) {  // diagonal: mask s_abs > q_abs
#pragma unroll
        for (int r16 = 0; r16 < 16; r16++) {
          int s_abs = j0 + shalf * 32 + (r16 & 3) + 8 * (r16 >> 2) + 4 * hi;
          if (s_abs > q_abs) s_acc[r16] = -__builtin_inff();
        }
      }

      // fixed-max: p = exp2(s - 20); in-lane partial l
      float p[16];
      float rsum = 0.f;
#pragma unroll
      for (int r16 = 0; r16 < 16; r16++) {
        p[r16] = __builtin_amdgcn_exp2f(s_acc[r16] - MFIX);
        rsum += p[r16];
      }
      l_i += rsum;

      // pack to bf16 pairs; exchange with lane^32 to build PV B-frags in-register
      u32 a[8], xch[8];
#pragma unroll
      for (int g = 0; g < 8; g++)
        a[g] = (__builtin_bit_cast(u32, p[2 * g]) >> 16) |
               (__builtin_bit_cast(u32, p[2 * g + 1]) & 0xffff0000u);
#pragma unroll
      for (int g = 0; g < 8; g++) xch[g] = __shfl_xor(a[g], 32);

      // O^T += V^T · P : per ks (s 16-chunk), B[k=s_rel][n=q]
      __builtin_amdgcn_s_setprio(1);
#pragma unroll
      for (int ks = 0; ks < 2; ks++) {
        uint4 fu;
        fu.x = hi ? xch[4 * ks + 2] : a[4 * ks + 0];
        fu.y = hi ? xch[4 * ks + 3] : a[4 * ks + 1];
        fu.z = hi ? a[4 * ks + 2] : xch[4 * ks + 0];
        fu.w = hi ? a[4 * ks + 3] : xch[4 * ks + 1];
        bf16x8 bp = __builtin_bit_cast(bf16x8, fu);
        const int ch = shalf * 4 + ks * 2 + hi;
        {
          int vrow = l31;  // d 0..31
          bf16x8 av = ldfrag(Vts + vrow * 64 + ((ch ^ (vrow & 7)) << 3));
          o0 = __builtin_amdgcn_mfma_f32_32x32x16_bf16(av, bp, o0, 0, 0, 0);
        }
        {
          int vrow = 32 + l31;  // d 32..63
          bf16x8 av = ldfrag(Vts + vrow * 64 + ((ch ^ (vrow & 7)) << 3));
          o1 = __builtin_amdgcn_mfma_f32_32x32x16_bf16(av, bp, o1, 0, 0, 0);
        }
      }
      __builtin_amdgcn_s_setprio(0);
    }

    // combine s-half partials: wave pairs (0,2),(1,3) share q; fixed-max => ADD
    __syncthreads();  // all waves done with Ks/Vts (Lo aliases them)
    if (shalf) {
      float* base = Lo + qhalf * 2048 + lane * 32;
#pragma unroll
      for (int g = 0; g < 4; g++) {
        float4 v = {o0[4 * g + 0], o0[4 * g + 1], o0[4 * g + 2], o0[4 * g + 3]};
        *(float4*)(base + ((g ^ (lane & 7)) << 2)) = v;
      }
#pragma unroll
      for (int g = 4; g < 8; g++) {
        float4 v = {o1[4 * g - 16], o1[4 * g - 15], o1[4 * g - 14], o1[4 * g - 13]};
        *(float4*)(base + ((g ^ (lane & 7)) << 2)) = v;
      }
      Ll[qhalf * 64 + lane] = l_i;
    }
    __syncthreads();
    if (!shalf) {
      float* base = Lo + qhalf * 2048 + lane * 32;
#pragma unroll
      for (int g = 0; g < 4; g++) {
        float4 v = *(float4*)(base + ((g ^ (lane & 7)) << 2));
        o0[4 * g + 0] += v.x; o0[4 * g + 1] += v.y;
        o0[4 * g + 2] += v.z; o0[4 * g + 3] += v.w;
      }
#pragma unroll
      for (int g = 4; g < 8; g++) {
        float4 v = *(float4*)(base + ((g ^ (lane & 7)) << 2));
        o1[4 * g - 16] += v.x; o1[4 * g - 15] += v.y;
        o1[4 * g - 14] += v.z; o1[4 * g - 13] += v.w;
      }
      l_i += Ll[qhalf * 64 + lane];
      l_i += __shfl_xor(l_i, 32);  // combine hi halves (same q)
      float inv = 1.0f / l_i;
      u16* orow = AO + ((size_t)bb * T_ + q_abs) * E_ + h * DH;
#pragma unroll
      for (int g = 0; g < 4; g++) {
        uint2 pk;
        pk.x = (u32)f2bf(o0[4 * g + 0] * inv) | ((u32)f2bf(o0[4 * g + 1] * inv) << 16);
        pk.y = (u32)f2bf(o0[4 * g + 2] * inv) | ((u32)f2bf(o0[4 * g + 3] * inv) << 16);
        *(uint2*)(orow + 8 * g + 4 * hi) = pk;
        pk.x = (u32)f2bf(o1[4 * g + 0] * inv) | ((u32)f2bf(o1[4 * g + 1] * inv) << 16);
        pk.y = (u32)f2bf(o1[4 * g + 2] * inv) | ((u32)f2bf(o1[4 * g + 3] * inv) << 16);
        *(uint2*)(orow + 32 + 8 * g + 4 * hi) = pk;
      }
    }
  }
}

// ---- output projection, 128x64 tiles, XCD-banded: out = AO @ wo^T + b ----
__global__ __launch_bounds__(256, 3) void k_oproj(const u16* __restrict__ AO, const u16* __restrict__ woB,
                                                  const float* __restrict__ bias, float* __restrict__ out) {
  __shared__ __align__(16) u16 As[128 * 64];  // 16 KB
  __shared__ __align__(16) u16 Bs[64 * 64];   //  8 KB
  const int tid = threadIdx.x;
  const int w = tid >> 6, lane = tid & 63, quad = lane >> 4, lr = lane & 15;
  const int wr = w >> 1, wc = w & 1;
  const int bid = blockIdx.x;
  const int xcd = bid & 7, bidx = bid >> 3;      // bidx in [0,64)
  const int r0 = (xcd * 4 + (bidx >> 4)) * 128;  // row-tile in [0,32)
  const int n0 = (bidx & 15) * 64;               // col-tile in [0,16)
  const int sr = lane >> 3, sc = lane & 7;

  f32x4 acc[4][2];
  const f32x4 z4 = {0.f, 0.f, 0.f, 0.f};
#pragma unroll
  for (int i = 0; i < 4; i++) {
    acc[i][0] = z4;
    acc[i][1] = z4;
  }

  for (int k0 = 0; k0 < E_; k0 += 64) {
    __syncthreads();
#pragma unroll
    for (int ii = 0; ii < 4; ii++) {  // A: 128 rows, wave stages 32
      int ra = w * 32 + ii * 8 + sr;
      gload_lds16(AO + (size_t)(r0 + ra) * E_ + k0 + ((sc ^ (ra & 7)) << 3),
                  As + (w * 32 + ii * 8) * 64);
    }
#pragma unroll
    for (int ii = 0; ii < 2; ii++) {  // B: 64 rows, wave stages 16
      int rb = w * 16 + ii * 8 + sr;
      gload_lds16(woB + (size_t)(n0 + rb) * E_ + k0 + ((sc ^ (rb & 7)) << 3),
                  Bs + (w * 16 + ii * 8) * 64);
    }
    __syncthreads();
#pragma unroll
    for (int kk = 0; kk < 2; kk++) {
      bf16x8 af[4], bfv[2];
#pragma unroll
      for (int rt = 0; rt < 4; rt++) {
        int row = wr * 64 + rt * 16 + lr;
        af[rt] = ldfrag(As + row * 64 + (((kk * 4 + quad) ^ (row & 7)) << 3));
      }
#pragma unroll
      for (int ct = 0; ct < 2; ct++) {
        int row = wc * 32 + ct * 16 + lr;
        bfv[ct] = ldfrag(Bs + row * 64 + (((kk * 4 + quad) ^ (row & 7)) << 3));
      }
#pragma unroll
      for (int rt = 0; rt < 4; rt++)
#pragma unroll
        for (int ct = 0; ct < 2; ct++)
          acc[rt][ct] = __builtin_amdgcn_mfma_f32_16x16x32_bf16(af[rt], bfv[ct], acc[rt][ct], 0, 0, 0);
    }
  }

#pragma unroll
  for (int ct = 0; ct < 2; ct++) {
    int col = n0 + wc * 32 + ct * 16 + lr;
    float bv = bias[col];
#pragma unroll
    for (int rt = 0; rt < 4; rt++)
#pragma unroll
      for (int r = 0; r < 4; r++) {
        int row = r0 + wr * 64 + rt * 16 + quad * 4 + r;
        out[(size_t)row * E_ + col] = acc[rt][ct][r] + bv;
      }
  }
}

extern "C" void kernel_launch(void* const* d_in, const int* in_sizes, int n_in,
                              void* d_out, int out_size, void* d_ws, size_t ws_size,
                              hipStream_t stream) {
  const float* x = (const float*)d_in[0];
  const float* Wq = (const float*)d_in[1];
  const float* Wk = (const float*)d_in[2];
  const float* Wv = (const float*)d_in[3];
  const float* wo_w = (const float*)d_in[4];
  const float* wo_b = (const float*)d_in[5];
  float* out = (float*)d_out;
  char* ws = (char*)d_ws;

  u16* xb  = (u16*)(ws + 0);          //  8 MiB: x bf16 [B,T,E]
  u16* wT  = (u16*)(ws + 8388608);    //  6 MiB: [3][H,Dh,E] bf16
  u16* woB = (u16*)(ws + 14680064);   //  2 MiB: wo bf16 [E,E]
  u16* Qb  = (u16*)(ws + 16777216);   //  8 MiB: Q [B,H,T,Dh] (pre-scaled 0.125*log2e)
  u16* Kb  = (u16*)(ws + 25165824);   //  8 MiB: K [B,H,T,Dh]
  u16* VbT = (u16*)(ws + 33554432);   //  8 MiB: V^T [B,H,Dh,T]
  u16* AO  = (u16*)(ws + 41943040);   //  8 MiB: attn out bf16 [B,T,E]

  k_conv_all<<<3328, 256, 0, stream>>>(x, Wq, Wk, Wv, wo_w, xb, wT, woB);
  k_qkv<<<768, 256, 0, stream>>>(xb, wT, Qb, Kb, VbT);
  k_attn<<<512, 256, 0, stream>>>(Qb, Kb, VbT, AO);
  k_oproj<<<512, 256, 0, stream>>>(AO, woB, wo_b, out);
}